// Round 12
// baseline (175.005 us; speedup 1.0000x reference)
//
#include <hip/hip_runtime.h>
#include <stdint.h>

typedef unsigned short u16t;
typedef short s8v __attribute__((ext_vector_type(8)));
typedef float f4v __attribute__((ext_vector_type(4)));

#define MFMA16 __builtin_amdgcn_mfma_f32_16x16x32_bf16
#define QKN (16*4*512*64)

__device__ __forceinline__ u16t f2bf(float f) {
  unsigned u = __builtin_bit_cast(unsigned, f);
  u += 0x7fffu + ((u >> 16) & 1u);          // RNE
  return (u16t)(u >> 16);
}

// ---------------------------------------------------------------------------
// prep_kernel: z<4 = Weff GEMM, z==4 = mask_norm, z in [5,13) = emb f32->bf16
// pre-conversion (128 blocks, runs concurrent with weff).
__global__ __launch_bounds__(256) void prep_kernel(
    const float* __restrict__ Wiqk, const float* __restrict__ Wqi, const float* __restrict__ Wki,
    const float* __restrict__ Wdqk, const float* __restrict__ Wqd, const float* __restrict__ Wkd,
    u16t* __restrict__ weffT, const int* __restrict__ mraw, int* __restrict__ mdst,
    const float* __restrict__ emb, u16t* __restrict__ embh) {
  __shared__ float At[16][65];
  __shared__ float Bt[16][65];
  __shared__ int mode;   // 0=int32, 1=bytes, 2=float32
  const int tid = threadIdx.x;

  if (blockIdx.z >= 5) {
    const int g2 = (blockIdx.z - 5) * 16 + blockIdx.y * 4 + blockIdx.x;  // 0..127
#pragma unroll
    for (int it = 0; it < 8; ++it) {
      size_t idx = (size_t)g2 * 16384 + it * 2048 + tid * 8;
      float4 x0 = *(const float4*)(emb + idx);
      float4 x1 = *(const float4*)(emb + idx + 4);
      unsigned p0, p1, p2, p3;
      asm("v_cvt_pk_bf16_f32 %0, %1, %2" : "=v"(p0) : "v"(x0.x), "v"(x0.y));
      asm("v_cvt_pk_bf16_f32 %0, %1, %2" : "=v"(p1) : "v"(x0.z), "v"(x0.w));
      asm("v_cvt_pk_bf16_f32 %0, %1, %2" : "=v"(p2) : "v"(x1.x), "v"(x1.y));
      asm("v_cvt_pk_bf16_f32 %0, %1, %2" : "=v"(p3) : "v"(x1.z), "v"(x1.w));
      *(uint4*)(embh + idx) = make_uint4(p0, p1, p2, p3);
    }
    return;
  }

  if (blockIdx.z == 4) {
    if (tid == 0) mode = 0;
    __syncthreads();
    unsigned v0 = (unsigned)mraw[tid], v1 = (unsigned)mraw[tid + 256];
    if (v0 == 0x3F800000u || v1 == 0x3F800000u) mode = 2;   // benign race
    __syncthreads();
    if (mode == 0 && (v0 > 1u || v1 > 1u)) mode = 1;
    __syncthreads();
    const int g = blockIdx.y * 4 + blockIdx.x;
#pragma unroll
    for (int i = 0; i < 2; ++i) {
      int idx = g * 512 + i * 256 + tid;
      int m;
      if (mode == 2)      m = (((const float*)mraw)[idx] != 0.0f) ? 1 : 0;
      else if (mode == 1) m = ((const unsigned char*)mraw)[idx];
      else                m = mraw[idx];
      mdst[idx] = m;
    }
    return;
  }

  const int n0 = blockIdx.x * 64;
  const int d0 = blockIdx.y * 64;
  const int p  = blockIdx.z;
  const float* A2  = (p == 0) ? Wqi : (p == 1) ? Wki : (p == 2) ? Wqd : Wkd;  // [t][n]
  const float* Wqk = (p < 2) ? Wiqk : Wdqk;                                    // [d][512]
  const int aoff = (p & 1) * 256;
  const int tx = tid & 15, ty = tid >> 4;

  float acc[4][4];
#pragma unroll
  for (int i = 0; i < 4; ++i)
#pragma unroll
    for (int j = 0; j < 4; ++j) acc[i][j] = 0.f;

  for (int k0 = 0; k0 < 256; k0 += 16) {
    __syncthreads();
    {
      int nn = tid & 63, kr = tid >> 6;
#pragma unroll
      for (int pass = 0; pass < 4; ++pass) {
        int kk = kr + pass * 4;
        At[kk][nn] = A2[(size_t)(k0 + kk) * 256 + n0 + nn];
      }
      int kk = tid & 15, dr = tid >> 4;
#pragma unroll
      for (int pass = 0; pass < 4; ++pass) {
        int dd = dr + pass * 16;
        Bt[kk][dd] = Wqk[(size_t)(d0 + dd) * 512 + aoff + k0 + kk];
      }
    }
    __syncthreads();
#pragma unroll
    for (int kk = 0; kk < 16; ++kk) {
      float a[4], b[4];
#pragma unroll
      for (int i = 0; i < 4; ++i) a[i] = At[kk][ty * 4 + i];
#pragma unroll
      for (int j = 0; j < 4; ++j) b[j] = Bt[kk][tx * 4 + j];
#pragma unroll
      for (int i = 0; i < 4; ++i)
#pragma unroll
        for (int j = 0; j < 4; ++j) acc[i][j] = fmaf(a[i], b[j], acc[i][j]);
    }
  }

#pragma unroll
  for (int i = 0; i < 4; ++i) {
    u16t h[4] = {f2bf(acc[i][0]), f2bf(acc[i][1]), f2bf(acc[i][2]), f2bf(acc[i][3])};
    *(uint2*)(&weffT[((size_t)(p * 256 + n0 + ty * 4 + i)) * 256 + d0 + tx * 4]) =
        *(const uint2*)h;
  }
}

// ---------------------------------------------------------------------------
// Projection GEMM: M=8192, N=1024, K=256. bf16 A (pre-converted), XCD swizzle.
// R12: Q-path scale = 0.125 * log2(e) so fused can use native v_exp_f32
// (exp2) with no per-element multiply.
__global__ __launch_bounds__(256) void proj_kernel(
    const u16t* __restrict__ embh, const u16t* __restrict__ weffT,
    const float* __restrict__ bq_inc, const float* __restrict__ bk_inc,
    const float* __restrict__ bq_dec, const float* __restrict__ bk_dec,
    u16t* __restrict__ qk) {
  __shared__ __align__(16) u16t As[128 * 40];
  __shared__ __align__(16) u16t Bs[128 * 40];
  const int t = threadIdx.x;
  const int f = (int)(blockIdx.x + gridDim.x * blockIdx.y);   // dispatch order
  const int xcd = f & 7, idx = f >> 3;
  const int ry = xcd * 8 + (idx & 7);    // r-block 0..63
  const int nx = idx >> 3;               // n-block 0..7
  const int n0 = nx * 128;
  const int r0 = ry * 128;
  const int bb = r0 >> 9;
  const int l0 = r0 & 511;
  const int lane = t & 63, wid = t >> 6;
  const int quad = lane >> 4, c15 = lane & 15;
  const int wm = wid >> 1, wn = wid & 1;

  f4v acc[4][4];
#pragma unroll
  for (int i = 0; i < 4; ++i)
#pragma unroll
    for (int j = 0; j < 4; ++j) acc[i][j] = f4v{0.f, 0.f, 0.f, 0.f};

  for (int k0 = 0; k0 < 256; k0 += 32) {
    __syncthreads();
#pragma unroll
    for (int i = 0; i < 2; ++i) {
      int c = t + i * 256;
      int m = c >> 2, off = (c & 3) * 8;
      *(uint4*)(&As[m * 40 + off]) =
          *(const uint4*)(embh + (size_t)((l0 + m) * 16 + bb) * 256 + k0 + off);
      *(uint4*)(&Bs[m * 40 + off]) =
          *(const uint4*)(weffT + (size_t)(n0 + m) * 256 + k0 + off);
    }
    __syncthreads();
    s8v af[4], bf[4];
#pragma unroll
    for (int mi = 0; mi < 4; ++mi)
      af[mi] = *(const s8v*)(&As[(wm * 64 + mi * 16 + c15) * 40 + quad * 8]);
#pragma unroll
    for (int ni = 0; ni < 4; ++ni)
      bf[ni] = *(const s8v*)(&Bs[(wn * 64 + ni * 16 + c15) * 40 + quad * 8]);
#pragma unroll
    for (int mi = 0; mi < 4; ++mi)
#pragma unroll
      for (int ni = 0; ni < 4; ++ni)
        acc[mi][ni] = MFMA16(af[mi], bf[ni], acc[mi][ni], 0, 0, 0);
  }

  const float* biasP[4] = {bq_inc, bk_inc, bq_dec, bk_dec};
#pragma unroll
  for (int ni = 0; ni < 4; ++ni) {
    int n = n0 + wn * 64 + ni * 16 + c15;
    int p = n >> 8, h = (n >> 6) & 3, tt = n & 63, jj = n & 255;
    float bias = biasP[p][jj];
    // Q paths carry 1/sqrt(hd) * log2(e): scores become log2-domain, fused
    // applies native exp2 (v_exp_f32) directly.
    const float osc = (p & 1) ? 1.0f : 0.18033688011112042f;
    u16t* dst = qk + (size_t)p * QKN;
#pragma unroll
    for (int mi = 0; mi < 4; ++mi) {
#pragma unroll
      for (int reg = 0; reg < 4; ++reg) {
        int l = l0 + wm * 64 + mi * 16 + quad * 4 + reg;
        dst[((size_t)(bb * 4 + h) * 512 + l) * 64 + tt] =
            f2bf((acc[mi][ni][reg] + bias) * osc);
      }
    }
  }
}

// ---------------------------------------------------------------------------
// Fused attention+epilogue = R11 (proven 44.2us) + three exact/cheap deltas:
//  - Qs XOR swizzle: stride 72*2B=144B made bank = 4*(c15+quad)%32 -> only 8
//    banks, ~8-way conflict on every a0/a1 ds_read_b128 (SQ_LDS_BANK_CONFLICT
//    430K). 16B-unit ^= (row&7) on write+read spreads to 2-way (free, m136).
//  - exp2f: scores arrive in log2 domain from proj -> native v_exp_f32, no
//    per-element multiply.
//  - sgn4 = +/-4 folded into inv (exact pow2 scaling; epilogue drops a mul).
__global__ __launch_bounds__(512) void fused_kernel(
    const u16t* __restrict__ qk, const int* __restrict__ mask,
    const int* __restrict__ src_bond, const float* __restrict__ Wc,
    const float* __restrict__ bc, float* __restrict__ out) {
  __shared__ __align__(16) u16t Qs[8 * 16 * 72];
  __shared__ int bondsL[96];
  __shared__ int mlds[512 + 16];
  __shared__ __align__(16) float rpart[2][16][8];   // [parity][l-row][wave]
  __shared__ float wlds[16];
  const int t = threadIdx.x;

  // XCD swizzle (bijective, 512 blocks = 8 XCDs x 64).
  const int f = (int)(blockIdx.x + gridDim.x * blockIdx.y);
  const int j = f >> 3;
  const int bb = (f & 7) * 2 + (j >> 5);
  const int l0 = (j & 31) * 16;

  const int lane = t & 63, wid = t >> 6;
  const int quad = lane >> 4, c15 = lane & 15;
  const int mbase = wid * 64 + c15;                      // + nt*16
  const u16t* Kblk = qk + (size_t)(bb * 4) * 512 * 64;   // block-uniform
  const int loff = mbase * 64 + quad * 8;                // per-lane elems

  // ---- stage Q (XOR-swizzled), masks, bonds, Wc into LDS ----
#pragma unroll
  for (int i = 0; i < 2; ++i) {
    int c = t + i * 512;
    int q = c >> 7, row = (c >> 3) & 15, u = c & 7;       // u = 16B unit
    const u16t* Qb = qk + (size_t)(2 * (q >> 2)) * QKN;
    *(uint4*)(&Qs[(q * 16 + row) * 72 + ((u ^ (row & 7)) * 8)]) =
        *(const uint4*)(Qb + ((size_t)(bb * 4 + (q & 3)) * 512 + l0 + row) * 64 + u * 8);
  }
  mlds[t] = mask[bb * 512 + t];
  if (t < 16) mlds[512 + t] = mask[bb * 512 + l0 + t];
  if (t < 96) bondsL[t] = src_bond[(size_t)(bb * 512 + l0 + t / 6) * 6 + (t % 6)];
  if (t >= 96 && t < 112) wlds[t - 96] = Wc[t - 96];

  // combo-0 K prefetch (completes during the staging barrier's drain)
  s8v kb0[4], kb1[4];
  {
    const u16t* Kq = Kblk + (size_t)1 * QKN;   // pp=0, h=0
#pragma unroll
    for (int nt = 0; nt < 4; ++nt) {
      kb0[nt] = *(const s8v*)(Kq + loff + nt * 1024);
      kb1[nt] = *(const s8v*)(Kq + loff + nt * 1024 + 32);
    }
  }

  __syncthreads();   // staging barrier (full drain; once)

  const int swz0 = (quad ^ (c15 & 7)) * 8;        // a0 unit, swizzled
  const int swz1 = ((quad + 4) ^ (c15 & 7)) * 8;  // a1 unit, swizzled

  bool mskm[4];
#pragma unroll
  for (int nt = 0; nt < 4; ++nt) mskm[nt] = (mlds[mbase + nt * 16] != 0);
  const bool allm = mskm[0] && mskm[1] && mskm[2] && mskm[3];
  bool lskip = true;
#pragma unroll
  for (int i = 0; i < 16; ++i) lskip = lskip && (mlds[512 + i] != 0);

  float dacc[4][4][4];   // [nt][reg][class]
#pragma unroll
  for (int nt = 0; nt < 4; ++nt)
#pragma unroll
    for (int r = 0; r < 4; ++r)
#pragma unroll
      for (int c = 0; c < 4; ++c) dacc[nt][r][c] = 0.f;

  // ================= single compute pass, 8 combos (rolled) ================
  if (!lskip) {
#pragma unroll 1
    for (int q = 0; q < 8; ++q) {
      const int h = q & 3;
      s8v a0 = *(const s8v*)(&Qs[(q * 16 + c15) * 72 + swz0]);
      s8v a1 = *(const s8v*)(&Qs[(q * 16 + c15) * 72 + swz1]);
      float wv[4];
#pragma unroll
      for (int c = 0; c < 4; ++c) wv[c] = wlds[h * 4 + c];

      float E[4][4];
      float rsum[4] = {0.f, 0.f, 0.f, 0.f};
      if (!allm) {
        f4v s[4];
#pragma unroll
        for (int nt = 0; nt < 4; ++nt) {
          f4v sacc = f4v{0.f, 0.f, 0.f, 0.f};
          sacc = MFMA16(a0, kb0[nt], sacc, 0, 0, 0);
          sacc = MFMA16(a1, kb1[nt], sacc, 0, 0, 0);
          s[nt] = sacc;
        }

        // issue next combo's K loads; stay in flight across the lgkm barrier
        if (q < 7) {
          const int qn = q + 1;
          const u16t* Kq = Kblk + (size_t)(2 * (qn >> 2) + 1) * QKN
                                + (size_t)(qn & 3) * (512 * 64);
#pragma unroll
          for (int nt = 0; nt < 4; ++nt) {
            kb0[nt] = *(const s8v*)(Kq + loff + nt * 1024);
            kb1[nt] = *(const s8v*)(Kq + loff + nt * 1024 + 32);
          }
        }

#pragma unroll
        for (int nt = 0; nt < 4; ++nt) {
#pragma unroll
          for (int reg = 0; reg < 4; ++reg) {
            float e = mskm[nt] ? 0.f : __builtin_exp2f(s[nt][reg]);
            E[nt][reg] = e;
            rsum[reg] += e;
          }
        }
#pragma unroll
        for (int reg = 0; reg < 4; ++reg) {
#pragma unroll
          for (int off = 1; off < 16; off <<= 1)
            rsum[reg] += __shfl_xor(rsum[reg], off);
        }
      } else {
#pragma unroll
        for (int nt = 0; nt < 4; ++nt)
#pragma unroll
          for (int reg = 0; reg < 4; ++reg) E[nt][reg] = 0.f;
      }
      if (c15 == 0) {
#pragma unroll
        for (int reg = 0; reg < 4; ++reg)
          rpart[q & 1][quad * 4 + reg][wid] = rsum[reg];
      }

      // LDS-only barrier: leaves global loads in flight.
      asm volatile("s_waitcnt lgkmcnt(0)" ::: "memory");
      __builtin_amdgcn_s_barrier();
      asm volatile("" ::: "memory");

      if (!allm) {
        const float sgn4 = (q < 4) ? 4.f : -4.f;   // exact pow2, folds the *4
        float inv[4];
#pragma unroll
        for (int reg = 0; reg < 4; ++reg) {
          const float4* rp = (const float4*)&rpart[q & 1][quad * 4 + reg][0];
          float4 s0 = rp[0], s1 = rp[1];
          float tot = s0.x + s0.y + s0.z + s0.w + s1.x + s1.y + s1.z + s1.w;
          inv[reg] = sgn4 * __builtin_amdgcn_rcpf(tot);
        }
#pragma unroll
        for (int nt = 0; nt < 4; ++nt) {
#pragma unroll
          for (int reg = 0; reg < 4; ++reg) {
            float P = E[nt][reg] * inv[reg];
#pragma unroll
            for (int c = 0; c < 4; ++c)
              dacc[nt][reg][c] = fmaf(P, wv[c], dacc[nt][reg][c]);
          }
        }
      }
    }
  }

  // ================= epilogue (single output burst at the end) =============
  float bc4[4];
#pragma unroll
  for (int c = 0; c < 4; ++c) bc4[c] = 4.f * bc[c];
  const float lgH = logf(0.7f + 1e-6f);
  const float lgM = logf(0.1f + 1e-6f);
  const float lgU = logf(0.25f + 1e-6f);

#pragma unroll
  for (int nt = 0; nt < 4; ++nt) {
    int m = mbase + nt * 16;
    bool padm = !mskm[nt];
#pragma unroll
    for (int reg = 0; reg < 4; ++reg) {
      int lloc = quad * 4 + reg;
      int l = l0 + lloc;
      bool padl = (mlds[512 + lloc] == 0);
      bool pm = padl && padm;
      int cnt = 0;
#pragma unroll
      for (int j6 = 0; j6 < 6; ++j6) cnt += (bondsL[lloc * 6 + j6] == m) ? 1 : 0;
      int cls = (pm && (m != l)) ? cnt : 0;
      float v[4];
#pragma unroll
      for (int c = 0; c < 4; ++c) {
        float lp = (cls >= 4) ? lgU : ((c == cls) ? lgH : lgM);
        float dv = pm ? (dacc[nt][reg][c] + bc4[c]) : 0.f;   // *4 pre-folded
        v[c] = lp + dv;
      }
      float4 o = make_float4(v[0], v[1], v[2], v[3]);
      *(float4*)(&out[((size_t)(bb * 512 + l) * 512 + m) * 4]) = o;
    }
  }
}

// ---------------------------------------------------------------------------
extern "C" void kernel_launch(void* const* d_in, const int* in_sizes, int n_in,
                              void* d_out, int out_size, void* d_ws, size_t ws_size,
                              hipStream_t stream) {
  (void)in_sizes; (void)n_in; (void)out_size; (void)ws_size;
  const float* emb      = (const float*)d_in[0];
  const int*   src_bond = (const int*)d_in[1];
  const int*   mask_raw = (const int*)d_in[2];
  const float* W_inc_qk = (const float*)d_in[3];
  const float* Wq_inc   = (const float*)d_in[4];
  const float* bq_inc   = (const float*)d_in[5];
  const float* Wk_inc   = (const float*)d_in[6];
  const float* bk_inc   = (const float*)d_in[7];
  const float* W_dec_qk = (const float*)d_in[8];
  const float* Wq_dec   = (const float*)d_in[9];
  const float* bq_dec   = (const float*)d_in[10];
  const float* Wk_dec   = (const float*)d_in[11];
  const float* bk_dec   = (const float*)d_in[12];
  const float* Wc       = (const float*)d_in[13];
  const float* bc       = (const float*)d_in[14];
  float* out = (float*)d_out;

  char* ws = (char*)d_ws;
  int*   wsMask = (int*)ws;                                        // 32 KiB
  u16t*  weffT  = (u16t*)(ws + 32768);                             // 512 KiB
  u16t*  qk     = (u16t*)(ws + 32768 + 524288);                    // 16 MiB (4 bufs)
  u16t*  embh   = (u16t*)(ws + 32768 + 524288 + 16777216);         // 4 MiB

  hipLaunchKernelGGL(prep_kernel, dim3(4, 4, 13), dim3(256), 0, stream,
                     W_inc_qk, Wq_inc, Wk_inc, W_dec_qk, Wq_dec, Wk_dec, weffT,
                     mask_raw, wsMask, emb, embh);
  hipLaunchKernelGGL(proj_kernel, dim3(8, 64), dim3(256), 0, stream,
                     embh, weffT, bq_inc, bk_inc, bq_dec, bk_dec, qk);
  hipLaunchKernelGGL(fused_kernel, dim3(32, 16), dim3(512), 0, stream,
                     qk, wsMask, src_bond, Wc, bc, out);
}

// Round 13
// 172.768 us; speedup vs baseline: 1.0129x; 1.0129x over previous
//
#include <hip/hip_runtime.h>
#include <stdint.h>

typedef unsigned short u16t;
typedef short s8v __attribute__((ext_vector_type(8)));
typedef float f4v __attribute__((ext_vector_type(4)));

#define MFMA16 __builtin_amdgcn_mfma_f32_16x16x32_bf16
#define QKN (16*4*512*64)

__device__ __forceinline__ u16t f2bf(float f) {
  unsigned u = __builtin_bit_cast(unsigned, f);
  u += 0x7fffu + ((u >> 16) & 1u);          // RNE
  return (u16t)(u >> 16);
}

// ---------------------------------------------------------------------------
// prep_kernel: z<4 = Weff GEMM, z==4 = mask_norm, z in [5,13) = emb f32->bf16
// pre-conversion (128 blocks, runs concurrent with weff).
__global__ __launch_bounds__(256) void prep_kernel(
    const float* __restrict__ Wiqk, const float* __restrict__ Wqi, const float* __restrict__ Wki,
    const float* __restrict__ Wdqk, const float* __restrict__ Wqd, const float* __restrict__ Wkd,
    u16t* __restrict__ weffT, const int* __restrict__ mraw, int* __restrict__ mdst,
    const float* __restrict__ emb, u16t* __restrict__ embh) {
  __shared__ float At[16][65];
  __shared__ float Bt[16][65];
  __shared__ int mode;   // 0=int32, 1=bytes, 2=float32
  const int tid = threadIdx.x;

  if (blockIdx.z >= 5) {
    const int g2 = (blockIdx.z - 5) * 16 + blockIdx.y * 4 + blockIdx.x;  // 0..127
#pragma unroll
    for (int it = 0; it < 8; ++it) {
      size_t idx = (size_t)g2 * 16384 + it * 2048 + tid * 8;
      float4 x0 = *(const float4*)(emb + idx);
      float4 x1 = *(const float4*)(emb + idx + 4);
      unsigned p0, p1, p2, p3;
      asm("v_cvt_pk_bf16_f32 %0, %1, %2" : "=v"(p0) : "v"(x0.x), "v"(x0.y));
      asm("v_cvt_pk_bf16_f32 %0, %1, %2" : "=v"(p1) : "v"(x0.z), "v"(x0.w));
      asm("v_cvt_pk_bf16_f32 %0, %1, %2" : "=v"(p2) : "v"(x1.x), "v"(x1.y));
      asm("v_cvt_pk_bf16_f32 %0, %1, %2" : "=v"(p3) : "v"(x1.z), "v"(x1.w));
      *(uint4*)(embh + idx) = make_uint4(p0, p1, p2, p3);
    }
    return;
  }

  if (blockIdx.z == 4) {
    if (tid == 0) mode = 0;
    __syncthreads();
    unsigned v0 = (unsigned)mraw[tid], v1 = (unsigned)mraw[tid + 256];
    if (v0 == 0x3F800000u || v1 == 0x3F800000u) mode = 2;   // benign race
    __syncthreads();
    if (mode == 0 && (v0 > 1u || v1 > 1u)) mode = 1;
    __syncthreads();
    const int g = blockIdx.y * 4 + blockIdx.x;
#pragma unroll
    for (int i = 0; i < 2; ++i) {
      int idx = g * 512 + i * 256 + tid;
      int m;
      if (mode == 2)      m = (((const float*)mraw)[idx] != 0.0f) ? 1 : 0;
      else if (mode == 1) m = ((const unsigned char*)mraw)[idx];
      else                m = mraw[idx];
      mdst[idx] = m;
    }
    return;
  }

  const int n0 = blockIdx.x * 64;
  const int d0 = blockIdx.y * 64;
  const int p  = blockIdx.z;
  const float* A2  = (p == 0) ? Wqi : (p == 1) ? Wki : (p == 2) ? Wqd : Wkd;  // [t][n]
  const float* Wqk = (p < 2) ? Wiqk : Wdqk;                                    // [d][512]
  const int aoff = (p & 1) * 256;
  const int tx = tid & 15, ty = tid >> 4;

  float acc[4][4];
#pragma unroll
  for (int i = 0; i < 4; ++i)
#pragma unroll
    for (int j = 0; j < 4; ++j) acc[i][j] = 0.f;

  for (int k0 = 0; k0 < 256; k0 += 16) {
    __syncthreads();
    {
      int nn = tid & 63, kr = tid >> 6;
#pragma unroll
      for (int pass = 0; pass < 4; ++pass) {
        int kk = kr + pass * 4;
        At[kk][nn] = A2[(size_t)(k0 + kk) * 256 + n0 + nn];
      }
      int kk = tid & 15, dr = tid >> 4;
#pragma unroll
      for (int pass = 0; pass < 4; ++pass) {
        int dd = dr + pass * 16;
        Bt[kk][dd] = Wqk[(size_t)(d0 + dd) * 512 + aoff + k0 + kk];
      }
    }
    __syncthreads();
#pragma unroll
    for (int kk = 0; kk < 16; ++kk) {
      float a[4], b[4];
#pragma unroll
      for (int i = 0; i < 4; ++i) a[i] = At[kk][ty * 4 + i];
#pragma unroll
      for (int j = 0; j < 4; ++j) b[j] = Bt[kk][tx * 4 + j];
#pragma unroll
      for (int i = 0; i < 4; ++i)
#pragma unroll
        for (int j = 0; j < 4; ++j) acc[i][j] = fmaf(a[i], b[j], acc[i][j]);
    }
  }

#pragma unroll
  for (int i = 0; i < 4; ++i) {
    u16t h[4] = {f2bf(acc[i][0]), f2bf(acc[i][1]), f2bf(acc[i][2]), f2bf(acc[i][3])};
    *(uint2*)(&weffT[((size_t)(p * 256 + n0 + ty * 4 + i)) * 256 + d0 + tx * 4]) =
        *(const uint2*)h;
  }
}

// ---------------------------------------------------------------------------
// Projection GEMM: M=8192, N=1024, K=256. bf16 A (pre-converted), XCD swizzle.
// Q-path scale = 0.125 * log2(e): scores in log2 domain -> fused uses native
// v_exp_f32 (exp2) with no per-element multiply.
__global__ __launch_bounds__(256) void proj_kernel(
    const u16t* __restrict__ embh, const u16t* __restrict__ weffT,
    const float* __restrict__ bq_inc, const float* __restrict__ bk_inc,
    const float* __restrict__ bq_dec, const float* __restrict__ bk_dec,
    u16t* __restrict__ qk) {
  __shared__ __align__(16) u16t As[128 * 40];
  __shared__ __align__(16) u16t Bs[128 * 40];
  const int t = threadIdx.x;
  const int f = (int)(blockIdx.x + gridDim.x * blockIdx.y);   // dispatch order
  const int xcd = f & 7, idx = f >> 3;
  const int ry = xcd * 8 + (idx & 7);    // r-block 0..63
  const int nx = idx >> 3;               // n-block 0..7
  const int n0 = nx * 128;
  const int r0 = ry * 128;
  const int bb = r0 >> 9;
  const int l0 = r0 & 511;
  const int lane = t & 63, wid = t >> 6;
  const int quad = lane >> 4, c15 = lane & 15;
  const int wm = wid >> 1, wn = wid & 1;

  f4v acc[4][4];
#pragma unroll
  for (int i = 0; i < 4; ++i)
#pragma unroll
    for (int j = 0; j < 4; ++j) acc[i][j] = f4v{0.f, 0.f, 0.f, 0.f};

  for (int k0 = 0; k0 < 256; k0 += 32) {
    __syncthreads();
#pragma unroll
    for (int i = 0; i < 2; ++i) {
      int c = t + i * 256;
      int m = c >> 2, off = (c & 3) * 8;
      *(uint4*)(&As[m * 40 + off]) =
          *(const uint4*)(embh + (size_t)((l0 + m) * 16 + bb) * 256 + k0 + off);
      *(uint4*)(&Bs[m * 40 + off]) =
          *(const uint4*)(weffT + (size_t)(n0 + m) * 256 + k0 + off);
    }
    __syncthreads();
    s8v af[4], bf[4];
#pragma unroll
    for (int mi = 0; mi < 4; ++mi)
      af[mi] = *(const s8v*)(&As[(wm * 64 + mi * 16 + c15) * 40 + quad * 8]);
#pragma unroll
    for (int ni = 0; ni < 4; ++ni)
      bf[ni] = *(const s8v*)(&Bs[(wn * 64 + ni * 16 + c15) * 40 + quad * 8]);
#pragma unroll
    for (int mi = 0; mi < 4; ++mi)
#pragma unroll
      for (int ni = 0; ni < 4; ++ni)
        acc[mi][ni] = MFMA16(af[mi], bf[ni], acc[mi][ni], 0, 0, 0);
  }

  const float* biasP[4] = {bq_inc, bk_inc, bq_dec, bk_dec};
#pragma unroll
  for (int ni = 0; ni < 4; ++ni) {
    int n = n0 + wn * 64 + ni * 16 + c15;
    int p = n >> 8, h = (n >> 6) & 3, tt = n & 63, jj = n & 255;
    float bias = biasP[p][jj];
    const float osc = (p & 1) ? 1.0f : 0.18033688011112042f;  // 1/8 * log2(e)
    u16t* dst = qk + (size_t)p * QKN;
#pragma unroll
    for (int mi = 0; mi < 4; ++mi) {
#pragma unroll
      for (int reg = 0; reg < 4; ++reg) {
        int l = l0 + wm * 64 + mi * 16 + quad * 4 + reg;
        dst[((size_t)(bb * 4 + h) * 512 + l) * 64 + tt] =
            f2bf((acc[mi][ni][reg] + bias) * osc);
      }
    }
  }
}

// ---------------------------------------------------------------------------
// Fused attention+epilogue = R11's proven structure (44.2us best):
//  - LINEAR Qs staging/reads (R12's XOR swizzle REVERTED: it raised
//    SQ_LDS_BANK_CONFLICT 430K->630K via the write-side pattern),
//  - exp2 on log2-domain scores (no per-element multiply),
//  - sgn4 = +/-4 folded into inv (exact pow2),
//  - lgkmcnt-only reduce barriers, K prefetch across barriers,
//  - exact dynamic mask skips (all-masked wave / all-masked l-tile),
//  - single output burst at the very end (R3 lesson).
__global__ __launch_bounds__(512) void fused_kernel(
    const u16t* __restrict__ qk, const int* __restrict__ mask,
    const int* __restrict__ src_bond, const float* __restrict__ Wc,
    const float* __restrict__ bc, float* __restrict__ out) {
  __shared__ __align__(16) u16t Qs[8 * 16 * 72];
  __shared__ int bondsL[96];
  __shared__ int mlds[512 + 16];
  __shared__ __align__(16) float rpart[2][16][8];   // [parity][l-row][wave]
  __shared__ float wlds[16];
  const int t = threadIdx.x;

  // XCD swizzle (bijective, 512 blocks = 8 XCDs x 64).
  const int f = (int)(blockIdx.x + gridDim.x * blockIdx.y);
  const int j = f >> 3;
  const int bb = (f & 7) * 2 + (j >> 5);
  const int l0 = (j & 31) * 16;

  const int lane = t & 63, wid = t >> 6;
  const int quad = lane >> 4, c15 = lane & 15;
  const int mbase = wid * 64 + c15;                      // + nt*16
  const u16t* Kblk = qk + (size_t)(bb * 4) * 512 * 64;   // block-uniform
  const int loff = mbase * 64 + quad * 8;                // per-lane elems

  // ---- stage Q (linear), masks, bonds, Wc into LDS ----
#pragma unroll
  for (int i = 0; i < 2; ++i) {
    int c = t + i * 512;
    int q = c >> 7, row = (c >> 3) & 15, off = (c & 7) * 8;
    const u16t* Qb = qk + (size_t)(2 * (q >> 2)) * QKN;
    *(uint4*)(&Qs[(q * 16 + row) * 72 + off]) =
        *(const uint4*)(Qb + ((size_t)(bb * 4 + (q & 3)) * 512 + l0 + row) * 64 + off);
  }
  mlds[t] = mask[bb * 512 + t];
  if (t < 16) mlds[512 + t] = mask[bb * 512 + l0 + t];
  if (t < 96) bondsL[t] = src_bond[(size_t)(bb * 512 + l0 + t / 6) * 6 + (t % 6)];
  if (t >= 96 && t < 112) wlds[t - 96] = Wc[t - 96];

  // combo-0 K prefetch (completes during the staging barrier's drain)
  s8v kb0[4], kb1[4];
  {
    const u16t* Kq = Kblk + (size_t)1 * QKN;   // pp=0, h=0
#pragma unroll
    for (int nt = 0; nt < 4; ++nt) {
      kb0[nt] = *(const s8v*)(Kq + loff + nt * 1024);
      kb1[nt] = *(const s8v*)(Kq + loff + nt * 1024 + 32);
    }
  }

  __syncthreads();   // staging barrier (full drain; once)

  bool mskm[4];
#pragma unroll
  for (int nt = 0; nt < 4; ++nt) mskm[nt] = (mlds[mbase + nt * 16] != 0);
  const bool allm = mskm[0] && mskm[1] && mskm[2] && mskm[3];
  bool lskip = true;
#pragma unroll
  for (int i = 0; i < 16; ++i) lskip = lskip && (mlds[512 + i] != 0);

  float dacc[4][4][4];   // [nt][reg][class]
#pragma unroll
  for (int nt = 0; nt < 4; ++nt)
#pragma unroll
    for (int r = 0; r < 4; ++r)
#pragma unroll
      for (int c = 0; c < 4; ++c) dacc[nt][r][c] = 0.f;

  // ================= single compute pass, 8 combos (rolled) ================
  if (!lskip) {
#pragma unroll 1
    for (int q = 0; q < 8; ++q) {
      const int h = q & 3;
      s8v a0 = *(const s8v*)(&Qs[(q * 16 + c15) * 72 + quad * 8]);
      s8v a1 = *(const s8v*)(&Qs[(q * 16 + c15) * 72 + 32 + quad * 8]);
      float wv[4];
#pragma unroll
      for (int c = 0; c < 4; ++c) wv[c] = wlds[h * 4 + c];

      float E[4][4];
      float rsum[4] = {0.f, 0.f, 0.f, 0.f};
      if (!allm) {
        f4v s[4];
#pragma unroll
        for (int nt = 0; nt < 4; ++nt) {
          f4v sacc = f4v{0.f, 0.f, 0.f, 0.f};
          sacc = MFMA16(a0, kb0[nt], sacc, 0, 0, 0);
          sacc = MFMA16(a1, kb1[nt], sacc, 0, 0, 0);
          s[nt] = sacc;
        }

        // issue next combo's K loads; stay in flight across the lgkm barrier
        if (q < 7) {
          const int qn = q + 1;
          const u16t* Kq = Kblk + (size_t)(2 * (qn >> 2) + 1) * QKN
                                + (size_t)(qn & 3) * (512 * 64);
#pragma unroll
          for (int nt = 0; nt < 4; ++nt) {
            kb0[nt] = *(const s8v*)(Kq + loff + nt * 1024);
            kb1[nt] = *(const s8v*)(Kq + loff + nt * 1024 + 32);
          }
        }

#pragma unroll
        for (int nt = 0; nt < 4; ++nt) {
#pragma unroll
          for (int reg = 0; reg < 4; ++reg) {
            float e = mskm[nt] ? 0.f : __builtin_exp2f(s[nt][reg]);
            E[nt][reg] = e;
            rsum[reg] += e;
          }
        }
#pragma unroll
        for (int reg = 0; reg < 4; ++reg) {
#pragma unroll
          for (int off = 1; off < 16; off <<= 1)
            rsum[reg] += __shfl_xor(rsum[reg], off);
        }
      } else {
#pragma unroll
        for (int nt = 0; nt < 4; ++nt)
#pragma unroll
          for (int reg = 0; reg < 4; ++reg) E[nt][reg] = 0.f;
      }
      if (c15 == 0) {
#pragma unroll
        for (int reg = 0; reg < 4; ++reg)
          rpart[q & 1][quad * 4 + reg][wid] = rsum[reg];
      }

      // LDS-only barrier: leaves global loads in flight.
      asm volatile("s_waitcnt lgkmcnt(0)" ::: "memory");
      __builtin_amdgcn_s_barrier();
      asm volatile("" ::: "memory");

      if (!allm) {
        const float sgn4 = (q < 4) ? 4.f : -4.f;   // exact pow2, folds the *4
        float inv[4];
#pragma unroll
        for (int reg = 0; reg < 4; ++reg) {
          const float4* rp = (const float4*)&rpart[q & 1][quad * 4 + reg][0];
          float4 s0 = rp[0], s1 = rp[1];
          float tot = s0.x + s0.y + s0.z + s0.w + s1.x + s1.y + s1.z + s1.w;
          inv[reg] = sgn4 * __builtin_amdgcn_rcpf(tot);
        }
#pragma unroll
        for (int nt = 0; nt < 4; ++nt) {
#pragma unroll
          for (int reg = 0; reg < 4; ++reg) {
            float P = E[nt][reg] * inv[reg];
#pragma unroll
            for (int c = 0; c < 4; ++c)
              dacc[nt][reg][c] = fmaf(P, wv[c], dacc[nt][reg][c]);
          }
        }
      }
    }
  }

  // ================= epilogue (single output burst at the end) =============
  float bc4[4];
#pragma unroll
  for (int c = 0; c < 4; ++c) bc4[c] = 4.f * bc[c];
  const float lgH = logf(0.7f + 1e-6f);
  const float lgM = logf(0.1f + 1e-6f);
  const float lgU = logf(0.25f + 1e-6f);

#pragma unroll
  for (int nt = 0; nt < 4; ++nt) {
    int m = mbase + nt * 16;
    bool padm = !mskm[nt];
#pragma unroll
    for (int reg = 0; reg < 4; ++reg) {
      int lloc = quad * 4 + reg;
      int l = l0 + lloc;
      bool padl = (mlds[512 + lloc] == 0);
      bool pm = padl && padm;
      int cnt = 0;
#pragma unroll
      for (int j6 = 0; j6 < 6; ++j6) cnt += (bondsL[lloc * 6 + j6] == m) ? 1 : 0;
      int cls = (pm && (m != l)) ? cnt : 0;
      float v[4];
#pragma unroll
      for (int c = 0; c < 4; ++c) {
        float lp = (cls >= 4) ? lgU : ((c == cls) ? lgH : lgM);
        float dv = pm ? (dacc[nt][reg][c] + bc4[c]) : 0.f;   // *4 pre-folded
        v[c] = lp + dv;
      }
      float4 o = make_float4(v[0], v[1], v[2], v[3]);
      *(float4*)(&out[((size_t)(bb * 512 + l) * 512 + m) * 4]) = o;
    }
  }
}

// ---------------------------------------------------------------------------
extern "C" void kernel_launch(void* const* d_in, const int* in_sizes, int n_in,
                              void* d_out, int out_size, void* d_ws, size_t ws_size,
                              hipStream_t stream) {
  (void)in_sizes; (void)n_in; (void)out_size; (void)ws_size;
  const float* emb      = (const float*)d_in[0];
  const int*   src_bond = (const int*)d_in[1];
  const int*   mask_raw = (const int*)d_in[2];
  const float* W_inc_qk = (const float*)d_in[3];
  const float* Wq_inc   = (const float*)d_in[4];
  const float* bq_inc   = (const float*)d_in[5];
  const float* Wk_inc   = (const float*)d_in[6];
  const float* bk_inc   = (const float*)d_in[7];
  const float* W_dec_qk = (const float*)d_in[8];
  const float* Wq_dec   = (const float*)d_in[9];
  const float* bq_dec   = (const float*)d_in[10];
  const float* Wk_dec   = (const float*)d_in[11];
  const float* bk_dec   = (const float*)d_in[12];
  const float* Wc       = (const float*)d_in[13];
  const float* bc       = (const float*)d_in[14];
  float* out = (float*)d_out;

  char* ws = (char*)d_ws;
  int*   wsMask = (int*)ws;                                        // 32 KiB
  u16t*  weffT  = (u16t*)(ws + 32768);                             // 512 KiB
  u16t*  qk     = (u16t*)(ws + 32768 + 524288);                    // 16 MiB (4 bufs)
  u16t*  embh   = (u16t*)(ws + 32768 + 524288 + 16777216);         // 4 MiB

  hipLaunchKernelGGL(prep_kernel, dim3(4, 4, 13), dim3(256), 0, stream,
                     W_inc_qk, Wq_inc, Wk_inc, W_dec_qk, Wq_dec, Wk_dec, weffT,
                     mask_raw, wsMask, emb, embh);
  hipLaunchKernelGGL(proj_kernel, dim3(8, 64), dim3(256), 0, stream,
                     embh, weffT, bq_inc, bk_inc, bq_dec, bk_dec, qk);
  hipLaunchKernelGGL(fused_kernel, dim3(32, 16), dim3(512), 0, stream,
                     qk, wsMask, src_bond, Wc, bc, out);
}